// Round 3
// baseline (283.349 us; speedup 1.0000x reference)
//
#include <hip/hip_runtime.h>
#include <hip/hip_cooperative_groups.h>
#include <math.h>

namespace cg = cooperative_groups;

#define Nn 6144
#define FIN 128
#define DMID 128
#define DHID 64
#define NH 4
#define NG 12
#define NB 512
#define NBLK 256
#define ALPHA 0.2f
#define EPSV 1e-9f

typedef __bf16 bf16x8 __attribute__((ext_vector_type(8)));
typedef float f32x4 __attribute__((ext_vector_type(4)));

union BU { bf16x8 v; uint u[4]; uint4 q; };

__device__ __forceinline__ float leaky(float x){ return x > 0.f ? x : ALPHA*x; }
__device__ __forceinline__ float eluf(float x){ return x > 0.f ? x : __expf(x)-1.f; }
__device__ __forceinline__ uint f2bf(float f){
  uint u = __float_as_uint(f);
  return (u + 0x7FFFu + ((u>>16)&1u)) >> 16;
}
__device__ __forceinline__ float wave_sum(float v){
  #pragma unroll
  for (int off=32; off; off>>=1) v += __shfl_xor(v, off);
  return v;
}
__device__ __forceinline__ float wave_max(float v){
  #pragma unroll
  for (int off=32; off; off>>=1) v = fmaxf(v, __shfl_xor(v, off));
  return v;
}

__global__ __launch_bounds__(256) void k_all(
    const float* __restrict__ x, const float* __restrict__ mask,
    const float* __restrict__ Wv, const float* __restrict__ bv,
    const float* __restrict__ W0, const float* __restrict__ al0, const float* __restrict__ ar0,
    const float* __restrict__ Wf, const float* __restrict__ alf, const float* __restrict__ arf,
    const float* __restrict__ W1, const float* __restrict__ b1,
    const float* __restrict__ W2, const float* __restrict__ b2,
    float* __restrict__ out,
    unsigned short* __restrict__ ftT, unsigned short* __restrict__ ftfT,
    float* __restrict__ h1, float* __restrict__ a1arr, float* __restrict__ a2arr,
    float* __restrict__ a1f, float* __restrict__ a2f,
    float* __restrict__ pmax, float* __restrict__ pmaxf, float* __restrict__ ppart)
{
  cg::grid_group grid = cg::this_grid();
  int b = blockIdx.x, t = threadIdx.x;
  int lane = t & 63, w = t >> 6;

  __shared__ float xs[8][FIN];
  __shared__ float hs[8][DMID];
  __shared__ float hsf[8][NH*DHID];
  __shared__ float dparts[4][4][2];
  __shared__ float s_acc[4][8][64][4];
  __shared__ float s_d[4][16];
  __shared__ float ps[DMID], ts[DMID];

  // ================= phase 1: h = relu(x@Wv+bv); ft0 = h@W0; a1/a2 dots; partial max
  {
    int hd = w, d = lane;
    float m8 = -INFINITY;
    for (int gi = 0; gi < 3; ++gi) {
      int i0 = (b + gi*NBLK) * 8;
      __syncthreads();
      for (int idx = t; idx < 8*FIN; idx += 256) xs[idx>>7][idx&127] = x[(size_t)i0*FIN + idx];
      __syncthreads();
      {
        int ch = t & 127, rg = t >> 7;
        float acc4[4];
        float bvv = bv[ch];
        #pragma unroll
        for (int q=0;q<4;++q) acc4[q]=bvv;
        #pragma unroll 4
        for (int k=0;k<FIN;++k){
          float wv = Wv[k*DMID + ch];
          #pragma unroll
          for (int q=0;q<4;++q) acc4[q] += xs[rg*4+q][k]*wv;
        }
        #pragma unroll
        for (int q=0;q<4;++q) hs[rg*4+q][ch] = fmaxf(acc4[q], 0.f);
      }
      __syncthreads();
      float facc[8]={0,0,0,0,0,0,0,0};
      const float* wp = W0 + (size_t)hd*(DMID*DHID) + d;
      #pragma unroll 4
      for (int k=0;k<DMID;++k){
        float wval = wp[(size_t)k*DHID];
        #pragma unroll
        for (int r=0;r<8;++r) facc[r] += hs[r][k]*wval;
      }
      {
        uint4 st;
        st.x = f2bf(facc[0]) | (f2bf(facc[1])<<16);
        st.y = f2bf(facc[2]) | (f2bf(facc[3])<<16);
        st.z = f2bf(facc[4]) | (f2bf(facc[5])<<16);
        st.w = f2bf(facc[6]) | (f2bf(facc[7])<<16);
        *reinterpret_cast<uint4*>(ftT + (size_t)t*Nn + i0) = st;
      }
      float alv = al0[hd*DHID+d], arv = ar0[hd*DHID+d];
      #pragma unroll
      for (int r=0;r<8;++r){
        float s1 = wave_sum(facc[r]*alv);
        float s2 = wave_sum(facc[r]*arv);
        if (d==0){ a1arr[hd*Nn + i0+r] = s1; a2arr[hd*Nn + i0+r] = s2; }
        m8 = fmaxf(m8, s2);
      }
    }
    if (lane == 0) pmax[hd*NBLK + b] = m8;
  }
  grid.sync();

  // ================= phase 2: attention layer 0 (MFMA), h1 = elu(attn@ft0)
  {
    int wid = b*4 + w;
    for (int task = wid; task < NG*NH*32; task += 1024) {
      int it = task & 31;
      int hh = (task>>5) & 3;
      int g  = task >> 7;
      int i0 = g*NB + it*16, jbase = g*NB;
      int row = lane & 15, kg = lane >> 4;
      float mxv = -INFINITY;
      #pragma unroll
      for (int q=0;q<4;++q) mxv = fmaxf(mxv, pmax[hh*NBLK + q*64 + lane]);
      mxv = wave_max(mxv);
      float a1v = a1arr[hh*Nn + i0 + row];
      float mv = leaky(a1v + mxv);
      f32x4 acc[4] = {{0,0,0,0},{0,0,0,0},{0,0,0,0},{0,0,0,0}};
      float dsum = 0.f;
      const float* mrow = mask + (size_t)(i0+row)*Nn;
      for (int js=0; js<NB; js+=32){
        int jc = jbase + js + kg*8;
        float4 mk0 = *reinterpret_cast<const float4*>(mrow + jc);
        float4 mk1 = *reinterpret_cast<const float4*>(mrow + jc + 4);
        float4 a20 = *reinterpret_cast<const float4*>(a2arr + hh*Nn + jc);
        float4 a21 = *reinterpret_cast<const float4*>(a2arr + hh*Nn + jc + 4);
        float a2l[8] = {a20.x,a20.y,a20.z,a20.w,a21.x,a21.y,a21.z,a21.w};
        float mkl[8] = {mk0.x,mk0.y,mk0.z,mk0.w,mk1.x,mk1.y,mk1.z,mk1.w};
        float wv[8];
        #pragma unroll
        for (int e=0;e<8;++e){
          float p = __expf(leaky(a1v + a2l[e]) - mv) * mkl[e];
          wv[e] = p; dsum += p;
        }
        BU A;
        #pragma unroll
        for (int q=0;q<4;++q) A.u[q] = f2bf(wv[2*q]) | (f2bf(wv[2*q+1])<<16);
        #pragma unroll
        for (int c=0;c<4;++c){
          BU B;
          B.q = *reinterpret_cast<const uint4*>(ftT + (size_t)(hh*DHID + c*16 + row)*Nn + jbase + js + kg*8);
          acc[c] = __builtin_amdgcn_mfma_f32_16x16x32_bf16(A.v, B.v, acc[c], 0, 0, 0);
        }
      }
      dsum += __shfl_xor(dsum, 16);
      dsum += __shfl_xor(dsum, 32);
      #pragma unroll
      for (int c=0;c<4;++c){
        #pragma unroll
        for (int reg=0;reg<4;++reg){
          float drow = __shfl(dsum, kg*4+reg) + EPSV;
          float o = eluf(acc[c][reg] / drow);
          h1[(size_t)(i0 + kg*4 + reg)*(NH*DHID) + hh*DHID + c*16 + row] = o;
        }
      }
    }
  }
  grid.sync();

  // ================= phase 3: ftf = h1@Wf -> bf16 T; a1f/a2f dots; partial max
  {
    float mloc = -INFINITY;
    for (int gi=0; gi<3; ++gi) {
      int i0 = (b + gi*NBLK) * 8;
      __syncthreads();
      for (int idx=t; idx<8*(NH*DHID); idx+=256) hsf[idx>>8][idx&255] = h1[(size_t)i0*(NH*DHID) + idx];
      __syncthreads();
      int ch = (w&1)*64 + lane;
      int r0 = (w>>1)*4;
      float f4[4] = {0,0,0,0};
      #pragma unroll 4
      for (int k=0;k<NH*DHID;++k){
        float wv = Wf[(size_t)k*DMID + ch];
        #pragma unroll
        for (int q=0;q<4;++q) f4[q] += hsf[r0+q][k]*wv;
      }
      {
        uint2 st2;
        st2.x = f2bf(f4[0]) | (f2bf(f4[1])<<16);
        st2.y = f2bf(f4[2]) | (f2bf(f4[3])<<16);
        *reinterpret_cast<uint2*>(ftfT + (size_t)ch*Nn + i0 + r0) = st2;
      }
      float alv = alf[ch], arv = arf[ch];
      #pragma unroll
      for (int q=0;q<4;++q){
        float s1 = wave_sum(f4[q]*alv);
        float s2 = wave_sum(f4[q]*arv);
        if (lane==0){ dparts[w][q][0]=s1; dparts[w][q][1]=s2; }
      }
      __syncthreads();
      if (t < 8){
        int hsel = (t>>2)*2, q = t&3;
        float v1 = dparts[hsel][q][0] + dparts[hsel+1][q][0];
        float v2 = dparts[hsel][q][1] + dparts[hsel+1][q][1];
        a1f[i0+t] = v1; a2f[i0+t] = v2;
        mloc = fmaxf(mloc, v2);
      }
    }
    if (t < 8){
      #pragma unroll
      for (int off=4; off; off>>=1) mloc = fmaxf(mloc, __shfl_xor(mloc, off));
      if (t==0) pmaxf[b] = mloc;
    }
  }
  grid.sync();

  // ================= phase 4: final attention (MFMA), 4 waves split j, pooled partials
  {
    int row = lane & 15, kg = lane >> 4;
    for (int task = b; task < NG*32; task += NBLK) {
      int it = task & 31, g = task >> 5;
      int i0 = g*NB + it*16, jbase = g*NB;
      float mxv = -INFINITY;
      #pragma unroll
      for (int q=0;q<4;++q) mxv = fmaxf(mxv, pmaxf[q*64+lane]);
      mxv = wave_max(mxv);
      float a1v = a1f[i0+row];
      float mv = leaky(a1v + mxv);
      f32x4 acc[8];
      #pragma unroll
      for (int c=0;c<8;++c) acc[c] = (f32x4){0,0,0,0};
      float dsum = 0.f;
      const float* mrow = mask + (size_t)(i0+row)*Nn;
      #pragma unroll 2
      for (int cc=0; cc<4; ++cc){
        int js = w*128 + cc*32;
        int jc = jbase + js + kg*8;
        float4 mk0 = *reinterpret_cast<const float4*>(mrow + jc);
        float4 mk1 = *reinterpret_cast<const float4*>(mrow + jc + 4);
        float4 a20 = *reinterpret_cast<const float4*>(a2f + jc);
        float4 a21 = *reinterpret_cast<const float4*>(a2f + jc + 4);
        float a2l[8] = {a20.x,a20.y,a20.z,a20.w,a21.x,a21.y,a21.z,a21.w};
        float mkl[8] = {mk0.x,mk0.y,mk0.z,mk0.w,mk1.x,mk1.y,mk1.z,mk1.w};
        float wv[8];
        #pragma unroll
        for (int e=0;e<8;++e){
          float p = __expf(leaky(a1v + a2l[e]) - mv) * mkl[e];
          wv[e] = p; dsum += p;
        }
        BU A;
        #pragma unroll
        for (int q=0;q<4;++q) A.u[q] = f2bf(wv[2*q]) | (f2bf(wv[2*q+1])<<16);
        #pragma unroll
        for (int c=0;c<8;++c){
          BU B;
          B.q = *reinterpret_cast<const uint4*>(ftfT + (size_t)(c*16 + row)*Nn + jbase + js + kg*8);
          acc[c] = __builtin_amdgcn_mfma_f32_16x16x32_bf16(A.v, B.v, acc[c], 0, 0, 0);
        }
      }
      dsum += __shfl_xor(dsum, 16);
      dsum += __shfl_xor(dsum, 32);
      if (lane < 16) s_d[w][lane] = dsum;
      #pragma unroll
      for (int c=0;c<8;++c)
        *reinterpret_cast<float4*>(&s_acc[w][c][lane][0]) = (float4){acc[c][0],acc[c][1],acc[c][2],acc[c][3]};
      __syncthreads();
      float dt = s_d[0][row] + s_d[1][row] + s_d[2][row] + s_d[3][row];
      #pragma unroll
      for (int ci=0; ci<2; ++ci){
        int c = w*2 + ci;
        float4 t0 = *reinterpret_cast<float4*>(&s_acc[0][c][lane][0]);
        float4 t1 = *reinterpret_cast<float4*>(&s_acc[1][c][lane][0]);
        float4 t2 = *reinterpret_cast<float4*>(&s_acc[2][c][lane][0]);
        float4 t3 = *reinterpret_cast<float4*>(&s_acc[3][c][lane][0]);
        float tot[4] = {t0.x+t1.x+t2.x+t3.x, t0.y+t1.y+t2.y+t3.y,
                        t0.z+t1.z+t2.z+t3.z, t0.w+t1.w+t2.w+t3.w};
        float psum = 0.f;
        #pragma unroll
        for (int reg=0;reg<4;++reg){
          float drow = __shfl(dt, kg*4+reg) + EPSV;
          psum += eluf(tot[reg] / drow);
        }
        psum += __shfl_xor(psum, 16);
        psum += __shfl_xor(psum, 32);
        if (lane < 16) ppart[(size_t)task*DMID + c*16 + lane] = psum;
      }
      __syncthreads();
    }
  }
  grid.sync();

  // ================= phase 5: reduce pooled partials + MLP
  if (b < NG) {
    if (t < DMID) {
      float s = 0.f;
      for (int it=0; it<32; ++it) s += ppart[(size_t)(b*32+it)*DMID + t];
      ps[t] = s;
    }
    __syncthreads();
    if (t < DMID) {
      float acc = b1[t];
      #pragma unroll 4
      for (int k=0;k<DMID;++k) acc += ps[k]*W1[k*DMID+t];
      ts[t] = fmaxf(acc, 0.f);
    }
    __syncthreads();
    if (t < 16) {
      float o = b2[t];
      #pragma unroll 4
      for (int k=0;k<DMID;++k) o += ts[k]*W2[k*16+t];
      out[b*16+t] = o;
    }
  }
}

extern "C" void kernel_launch(void* const* d_in, const int* in_sizes, int n_in,
                              void* d_out, int out_size, void* d_ws, size_t ws_size,
                              hipStream_t stream) {
  const float* x    = (const float*)d_in[0];
  const float* mask = (const float*)d_in[1];
  const float* Wv   = (const float*)d_in[3];
  const float* bv   = (const float*)d_in[4];
  const float* W0   = (const float*)d_in[5];
  const float* al0  = (const float*)d_in[6];
  const float* ar0  = (const float*)d_in[7];
  const float* Wf   = (const float*)d_in[8];
  const float* alf  = (const float*)d_in[9];
  const float* arf  = (const float*)d_in[10];
  const float* W1   = (const float*)d_in[11];
  const float* b1   = (const float*)d_in[12];
  const float* W2   = (const float*)d_in[13];
  const float* b2   = (const float*)d_in[14];
  float* out = (float*)d_out;

  float* ws = (float*)d_ws;
  float* h1            = ws;                              // 6144*256
  unsigned short* ftT  = (unsigned short*)(ws + 1572864); // 256*6144 u16
  unsigned short* ftfT = (unsigned short*)(ws + 2359296); // 128*6144 u16
  float* a1arr = ws + 2752512;   // 4*6144
  float* a2arr = ws + 2777088;   // 4*6144
  float* a1f   = ws + 2801664;   // 6144
  float* a2f   = ws + 2807808;   // 6144
  float* pmax  = ws + 2813952;   // 4*256
  float* pmaxf = ws + 2814976;   // 256
  float* ppart = ws + 2815232;   // 384*128

  void* args[] = {
    (void*)&x, (void*)&mask, (void*)&Wv, (void*)&bv, (void*)&W0, (void*)&al0, (void*)&ar0,
    (void*)&Wf, (void*)&alf, (void*)&arf, (void*)&W1, (void*)&b1, (void*)&W2, (void*)&b2,
    (void*)&out, (void*)&ftT, (void*)&ftfT, (void*)&h1, (void*)&a1arr, (void*)&a2arr,
    (void*)&a1f, (void*)&a2f, (void*)&pmax, (void*)&pmaxf, (void*)&ppart
  };
  hipLaunchCooperativeKernel((const void*)k_all, dim3(NBLK), dim3(256), args, 0, stream);
}

// Round 4
// 75.304 us; speedup vs baseline: 3.7627x; 3.7627x over previous
//
#include <hip/hip_runtime.h>
#include <math.h>

#define Nn 6144
#define FIN 128
#define DMID 128
#define DHID 64
#define NH 4
#define NG 12
#define NB 512
#define ALPHA 0.2f
#define EPSV 1e-9f

typedef __bf16 bf16x8 __attribute__((ext_vector_type(8)));
typedef float f32x4 __attribute__((ext_vector_type(4)));
typedef unsigned short ushort_t;

union BU { bf16x8 v; uint u[4]; uint4 q; };

__device__ __forceinline__ float leaky(float x){ return x > 0.f ? x : ALPHA*x; }
__device__ __forceinline__ float eluf(float x){ return x > 0.f ? x : __expf(x)-1.f; }
__device__ __forceinline__ uint f2bf(float f){
  uint u = __float_as_uint(f);
  return (u + 0x7FFFu + ((u>>16)&1u)) >> 16;
}
__device__ __forceinline__ float wave_max(float v){
  #pragma unroll
  for (int off=32; off; off>>=1) v = fmaxf(v, __shfl_xor(v, off));
  return v;
}

// ---------- K0: swizzle weights into MFMA B-fragment order (bf16) ----------
// layout per matrix: block (nt,kt) of 64 lanes x 16B; lane l holds W[kt*32+(l>>4)*8+e][nt*16+(l&15)]
__global__ __launch_bounds__(256) void k_prep(
    const float* __restrict__ Wv, const float* __restrict__ W0, const float* __restrict__ Wf,
    ushort_t* __restrict__ WvS, ushort_t* __restrict__ W0S, ushort_t* __restrict__ WfS){
  int tid = blockIdx.x*256 + threadIdx.x;   // 40*256 = 10240 = 160 blk * 64
  int lane = tid & 63, blk = tid >> 6;
  if (blk >= 160) return;
  const float* src; ushort_t* dst; int N; size_t off;
  if (blk < 32){
    int nt = blk>>2, kt = blk&3;
    src = Wv; dst = WvS; N = 128;
    off = ((size_t)(nt*4+kt)*64 + lane)*8;
    int col = nt*16 + (lane&15); int k0 = kt*32 + (lane>>4)*8;
    uint4 pk;
    uint e0=f2bf(src[(k0+0)*N+col]), e1=f2bf(src[(k0+1)*N+col]);
    uint e2=f2bf(src[(k0+2)*N+col]), e3=f2bf(src[(k0+3)*N+col]);
    uint e4=f2bf(src[(k0+4)*N+col]), e5=f2bf(src[(k0+5)*N+col]);
    uint e6=f2bf(src[(k0+6)*N+col]), e7=f2bf(src[(k0+7)*N+col]);
    pk.x=e0|(e1<<16); pk.y=e2|(e3<<16); pk.z=e4|(e5<<16); pk.w=e6|(e7<<16);
    *reinterpret_cast<uint4*>(dst + off) = pk;
  } else if (blk < 96){
    int b2 = blk-32; int hd = b2>>4, r = b2&15; int nt = r>>2, kt = r&3;
    src = W0 + (size_t)hd*128*64; dst = W0S + (size_t)hd*8192; N = 64;
    off = ((size_t)(nt*4+kt)*64 + lane)*8;
    int col = nt*16 + (lane&15); int k0 = kt*32 + (lane>>4)*8;
    uint4 pk;
    uint e0=f2bf(src[(k0+0)*N+col]), e1=f2bf(src[(k0+1)*N+col]);
    uint e2=f2bf(src[(k0+2)*N+col]), e3=f2bf(src[(k0+3)*N+col]);
    uint e4=f2bf(src[(k0+4)*N+col]), e5=f2bf(src[(k0+5)*N+col]);
    uint e6=f2bf(src[(k0+6)*N+col]), e7=f2bf(src[(k0+7)*N+col]);
    pk.x=e0|(e1<<16); pk.y=e2|(e3<<16); pk.z=e4|(e5<<16); pk.w=e6|(e7<<16);
    *reinterpret_cast<uint4*>(dst + off) = pk;
  } else {
    int b2 = blk-96; int nt = b2>>3, kt = b2&7;
    src = Wf; dst = WfS; N = 128;
    off = ((size_t)(nt*8+kt)*64 + lane)*8;
    int col = nt*16 + (lane&15); int k0 = kt*32 + (lane>>4)*8;
    uint4 pk;
    uint e0=f2bf(src[(k0+0)*N+col]), e1=f2bf(src[(k0+1)*N+col]);
    uint e2=f2bf(src[(k0+2)*N+col]), e3=f2bf(src[(k0+3)*N+col]);
    uint e4=f2bf(src[(k0+4)*N+col]), e5=f2bf(src[(k0+5)*N+col]);
    uint e6=f2bf(src[(k0+6)*N+col]), e7=f2bf(src[(k0+7)*N+col]);
    pk.x=e0|(e1<<16); pk.y=e2|(e3<<16); pk.z=e4|(e5<<16); pk.w=e6|(e7<<16);
    *reinterpret_cast<uint4*>(dst + off) = pk;
  }
}

// ---------- K1: fc1 + ft0 (MFMA) + dots + swizzled ftS ----------
__global__ __launch_bounds__(256) void k_f1(
    const float* __restrict__ x, const float* __restrict__ bv,
    const ushort_t* __restrict__ WvS, const ushort_t* __restrict__ W0S,
    const float* __restrict__ al0, const float* __restrict__ ar0,
    ushort_t* __restrict__ ftS, float* __restrict__ a1arr, float* __restrict__ a2arr,
    float* __restrict__ pmax0){
  int b = blockIdx.x; int i0 = b*16;
  int t = threadIdx.x, lane = t&63, w = t>>6;
  int row = lane&15, kg = lane>>4;
  __shared__ ushort_t xs[16][136];
  __shared__ ushort_t hts[16][136];
  __shared__ ushort_t fts[16][264];
  // stage x tile -> bf16 LDS
  {
    const float* xp = x + (size_t)i0*FIN + t*8;
    float4 f0 = *reinterpret_cast<const float4*>(xp);
    float4 f1 = *reinterpret_cast<const float4*>(xp+4);
    uint4 pk;
    pk.x = f2bf(f0.x)|(f2bf(f0.y)<<16); pk.y = f2bf(f0.z)|(f2bf(f0.w)<<16);
    pk.z = f2bf(f1.x)|(f2bf(f1.y)<<16); pk.w = f2bf(f1.z)|(f2bf(f1.w)<<16);
    *reinterpret_cast<uint4*>(&xs[t>>4][(t&15)*8]) = pk;
  }
  __syncthreads();
  // fc1: h = relu(x@Wv+bv); wave w -> n-tiles 2w, 2w+1
  {
    f32x4 acc2[2] = {{0,0,0,0},{0,0,0,0}};
    #pragma unroll
    for (int kt=0; kt<4; ++kt){
      bf16x8 aF = *reinterpret_cast<bf16x8*>(&xs[row][kt*32 + kg*8]);
      #pragma unroll
      for (int e2=0; e2<2; ++e2){
        int nt = w*2+e2;
        BU B; B.q = *reinterpret_cast<const uint4*>(WvS + ((size_t)(nt*4+kt)*64 + lane)*8);
        acc2[e2] = __builtin_amdgcn_mfma_f32_16x16x32_bf16(aF, B.v, acc2[e2], 0, 0, 0);
      }
    }
    #pragma unroll
    for (int e2=0; e2<2; ++e2){
      int nt = w*2+e2;
      float bvv = bv[nt*16+row];
      #pragma unroll
      for (int reg=0; reg<4; ++reg){
        float v = fmaxf(acc2[e2][reg]+bvv, 0.f);
        hts[kg*4+reg][nt*16+row] = (ushort_t)f2bf(v);
      }
    }
  }
  __syncthreads();
  // ft0: head = w; n-tiles 0..3 within head
  f32x4 acc4[4] = {{0,0,0,0},{0,0,0,0},{0,0,0,0},{0,0,0,0}};
  #pragma unroll
  for (int kt=0; kt<4; ++kt){
    bf16x8 aF = *reinterpret_cast<bf16x8*>(&hts[row][kt*32 + kg*8]);
    #pragma unroll
    for (int nt=0; nt<4; ++nt){
      BU B; B.q = *reinterpret_cast<const uint4*>(W0S + ((size_t)((w*4+nt)*4+kt)*64 + lane)*8);
      acc4[nt] = __builtin_amdgcn_mfma_f32_16x16x32_bf16(aF, B.v, acc4[nt], 0, 0, 0);
    }
  }
  // dots on C-fragments
  {
    float alv[4], arv[4];
    #pragma unroll
    for (int nt=0; nt<4; ++nt){ alv[nt] = al0[w*DHID+nt*16+row]; arv[nt] = ar0[w*DHID+nt*16+row]; }
    float s1[4]={0,0,0,0}, s2[4]={0,0,0,0};
    #pragma unroll
    for (int nt=0; nt<4; ++nt)
      #pragma unroll
      for (int reg=0; reg<4; ++reg){
        s1[reg] += acc4[nt][reg]*alv[nt];
        s2[reg] += acc4[nt][reg]*arv[nt];
      }
    #pragma unroll
    for (int off=1; off<16; off<<=1)
      #pragma unroll
      for (int reg=0; reg<4; ++reg){
        s1[reg] += __shfl_xor(s1[reg], off);
        s2[reg] += __shfl_xor(s2[reg], off);
      }
    if (row==0){
      #pragma unroll
      for (int reg=0; reg<4; ++reg){
        a1arr[w*Nn + i0 + kg*4+reg] = s1[reg];
        a2arr[w*Nn + i0 + kg*4+reg] = s2[reg];
      }
    }
    float mm = fmaxf(fmaxf(s2[0],s2[1]), fmaxf(s2[2],s2[3]));
    mm = fmaxf(mm, __shfl_xor(mm,16));
    mm = fmaxf(mm, __shfl_xor(mm,32));
    if (lane==0) pmax0[w*384 + b] = mm;
  }
  // fts LDS
  #pragma unroll
  for (int nt=0; nt<4; ++nt)
    #pragma unroll
    for (int reg=0; reg<4; ++reg)
      fts[kg*4+reg][w*DHID + nt*16+row] = (ushort_t)f2bf(acc4[nt][reg]);
  __syncthreads();
  // write swizzled ftS: thread t <-> channel
  {
    int ch = t, hd = ch>>6, ct = (ch>>4)&3, c = ch&15;
    int g = b>>5, ktj = (b&31)>>1, half = b&1;
    ushort_t v[16];
    #pragma unroll
    for (int i=0; i<16; ++i) v[i] = fts[i][ch];
    uint4 p0, p1;
    p0.x=(uint)v[0]|((uint)v[1]<<16);  p0.y=(uint)v[2]|((uint)v[3]<<16);
    p0.z=(uint)v[4]|((uint)v[5]<<16);  p0.w=(uint)v[6]|((uint)v[7]<<16);
    p1.x=(uint)v[8]|((uint)v[9]<<16);  p1.y=(uint)v[10]|((uint)v[11]<<16);
    p1.z=(uint)v[12]|((uint)v[13]<<16);p1.w=(uint)v[14]|((uint)v[15]<<16);
    size_t base = (((size_t)(g*4+hd)*16 + ktj)*4 + ct)*512;
    *reinterpret_cast<uint4*>(ftS + base + ((half*2+0)*16+c)*8) = p0;
    *reinterpret_cast<uint4*>(ftS + base + ((half*2+1)*16+c)*8) = p1;
  }
}

// ---------- K2: attention layer 0 (MFMA, swizzled B), h1b bf16 out ----------
__global__ __launch_bounds__(64) void k_attn0(
    const ushort_t* __restrict__ ftS, const float* __restrict__ a1arr,
    const float* __restrict__ a2arr, const float* __restrict__ pmax0,
    const float* __restrict__ mask, ushort_t* __restrict__ h1b){
  int bid = blockIdx.x;            // 12*4*32
  int it = bid & 31, hd = (bid>>5)&3, g = bid>>7;
  int i0 = g*NB + it*16, jbase = g*NB;
  int lane = threadIdx.x, row = lane&15, kg = lane>>4;
  float mxv = -INFINITY;
  #pragma unroll
  for (int q=0; q<6; ++q) mxv = fmaxf(mxv, pmax0[hd*384 + q*64 + lane]);
  mxv = wave_max(mxv);
  float a1v = a1arr[hd*Nn + i0 + row];
  float mv = leaky(a1v + mxv);
  f32x4 acc[4] = {{0,0,0,0},{0,0,0,0},{0,0,0,0},{0,0,0,0}};
  float dsum = 0.f;
  const float* mrow = mask + (size_t)(i0+row)*Nn;
  size_t fbase = (((size_t)(g*4+hd)*16)*4)*512;
  #pragma unroll 4
  for (int kt=0; kt<16; ++kt){
    int jc = jbase + kt*32 + kg*8;
    float4 mk0 = *reinterpret_cast<const float4*>(mrow + jc);
    float4 mk1 = *reinterpret_cast<const float4*>(mrow + jc + 4);
    float4 a20 = *reinterpret_cast<const float4*>(a2arr + hd*Nn + jc);
    float4 a21 = *reinterpret_cast<const float4*>(a2arr + hd*Nn + jc + 4);
    float a2l[8] = {a20.x,a20.y,a20.z,a20.w,a21.x,a21.y,a21.z,a21.w};
    float mkl[8] = {mk0.x,mk0.y,mk0.z,mk0.w,mk1.x,mk1.y,mk1.z,mk1.w};
    float wv[8];
    #pragma unroll
    for (int e=0;e<8;++e){
      float p = __expf(leaky(a1v + a2l[e]) - mv) * mkl[e];
      wv[e] = p; dsum += p;
    }
    BU A;
    #pragma unroll
    for (int q=0;q<4;++q) A.u[q] = f2bf(wv[2*q]) | (f2bf(wv[2*q+1])<<16);
    #pragma unroll
    for (int ct=0; ct<4; ++ct){
      BU B; B.q = *reinterpret_cast<const uint4*>(ftS + fbase + (size_t)(kt*4+ct)*512 + lane*8);
      acc[ct] = __builtin_amdgcn_mfma_f32_16x16x32_bf16(A.v, B.v, acc[ct], 0, 0, 0);
    }
  }
  dsum += __shfl_xor(dsum, 16);
  dsum += __shfl_xor(dsum, 32);
  #pragma unroll
  for (int ct=0; ct<4; ++ct)
    #pragma unroll
    for (int reg=0; reg<4; ++reg){
      float drow = __shfl(dsum, kg*4+reg) + EPSV;
      float o = eluf(acc[ct][reg] / drow);
      h1b[(size_t)(i0 + kg*4 + reg)*(NH*DHID) + hd*DHID + ct*16 + row] = (ushort_t)f2bf(o);
    }
}

// ---------- K3: fcf (MFMA) + dots + swizzled ftfS ----------
__global__ __launch_bounds__(256) void k_fcf(
    const ushort_t* __restrict__ h1b, const ushort_t* __restrict__ WfS,
    const float* __restrict__ alf, const float* __restrict__ arf,
    ushort_t* __restrict__ ftfS, float* __restrict__ a1f, float* __restrict__ a2f,
    float* __restrict__ pmaxf){
  int b = blockIdx.x; int i0 = b*16;
  int t = threadIdx.x, lane = t&63, w = t>>6;
  int row = lane&15, kg = lane>>4;
  __shared__ ushort_t hfs[16][264];
  __shared__ ushort_t fts[16][136];
  __shared__ float dpA[4][16], dpB[4][16];
  // stage h1b tile
  {
    const ushort_t* hp = h1b + (size_t)i0*(NH*DHID) + t*16;
    uint4 q0 = *reinterpret_cast<const uint4*>(hp);
    uint4 q1 = *reinterpret_cast<const uint4*>(hp+8);
    *reinterpret_cast<uint4*>(&hfs[t>>4][(t&15)*16]) = q0;
    *reinterpret_cast<uint4*>(&hfs[t>>4][(t&15)*16+8]) = q1;
  }
  __syncthreads();
  f32x4 acc2[2] = {{0,0,0,0},{0,0,0,0}};
  #pragma unroll
  for (int kt=0; kt<8; ++kt){
    bf16x8 aF = *reinterpret_cast<bf16x8*>(&hfs[row][kt*32 + kg*8]);
    #pragma unroll
    for (int e2=0; e2<2; ++e2){
      int nt = w*2+e2;
      BU B; B.q = *reinterpret_cast<const uint4*>(WfS + ((size_t)(nt*8+kt)*64 + lane)*8);
      acc2[e2] = __builtin_amdgcn_mfma_f32_16x16x32_bf16(aF, B.v, acc2[e2], 0, 0, 0);
    }
  }
  // dots (partial over this wave's 2 n-tiles) + fts LDS
  {
    float s1[4]={0,0,0,0}, s2[4]={0,0,0,0};
    #pragma unroll
    for (int e2=0; e2<2; ++e2){
      int nt = w*2+e2;
      float alv = alf[nt*16+row], arv = arf[nt*16+row];
      #pragma unroll
      for (int reg=0; reg<4; ++reg){
        s1[reg] += acc2[e2][reg]*alv;
        s2[reg] += acc2[e2][reg]*arv;
        fts[kg*4+reg][nt*16+row] = (ushort_t)f2bf(acc2[e2][reg]);
      }
    }
    #pragma unroll
    for (int off=1; off<16; off<<=1)
      #pragma unroll
      for (int reg=0; reg<4; ++reg){
        s1[reg] += __shfl_xor(s1[reg], off);
        s2[reg] += __shfl_xor(s2[reg], off);
      }
    if (row==0){
      #pragma unroll
      for (int reg=0; reg<4; ++reg){ dpA[w][kg*4+reg]=s1[reg]; dpB[w][kg*4+reg]=s2[reg]; }
    }
  }
  __syncthreads();
  if (t < 16){
    float v1 = dpA[0][t]+dpA[1][t]+dpA[2][t]+dpA[3][t];
    float v2 = dpB[0][t]+dpB[1][t]+dpB[2][t]+dpB[3][t];
    a1f[i0+t] = v1; a2f[i0+t] = v2;
    float m = v2;
    #pragma unroll
    for (int off=1; off<16; off<<=1) m = fmaxf(m, __shfl_xor(m, off));
    if (t==0) pmaxf[b] = m;
  }
  // write swizzled ftfS: thread t -> (ch = t>>1, half8 = t&1)
  {
    int ch = t>>1, half8 = t&1;
    int ct = ch>>4, c = ch&15;
    int g = b>>5, ktj = (b&31)>>1, half = b&1;
    ushort_t v[8];
    #pragma unroll
    for (int i=0; i<8; ++i) v[i] = fts[half8*8+i][ch];
    uint4 pk;
    pk.x=(uint)v[0]|((uint)v[1]<<16); pk.y=(uint)v[2]|((uint)v[3]<<16);
    pk.z=(uint)v[4]|((uint)v[5]<<16); pk.w=(uint)v[6]|((uint)v[7]<<16);
    int kslot = half*2 + half8;
    size_t base = ((size_t)(g*16+ktj)*8 + ct)*512;
    *reinterpret_cast<uint4*>(ftfS + base + (kslot*16+c)*8) = pk;
  }
}

// ---------- K4: final attention (MFMA) + pool partials ----------
__global__ __launch_bounds__(128) void k_attnf(
    const ushort_t* __restrict__ ftfS, const float* __restrict__ a1f,
    const float* __restrict__ a2f, const float* __restrict__ pmaxf,
    const float* __restrict__ mask, float* __restrict__ ppart){
  int b = blockIdx.x;             // 384: g, it
  int g = b>>5, it = b&31;
  int i0 = g*NB + it*16, jbase = g*NB;
  int t = threadIdx.x, lane = t&63, w = t>>6;
  int row = lane&15, kg = lane>>4;
  __shared__ float s_acc[2][8][64][4];
  __shared__ float s_d[2][16];
  float mxv = -INFINITY;
  #pragma unroll
  for (int q=0; q<6; ++q) mxv = fmaxf(mxv, pmaxf[q*64 + lane]);
  mxv = wave_max(mxv);
  float a1v = a1f[i0+row];
  float mv = leaky(a1v + mxv);
  f32x4 acc[8];
  #pragma unroll
  for (int ct=0; ct<8; ++ct) acc[ct] = (f32x4){0,0,0,0};
  float dsum = 0.f;
  const float* mrow = mask + (size_t)(i0+row)*Nn;
  #pragma unroll 2
  for (int c8=0; c8<8; ++c8){
    int kt = w*8 + c8;
    int jc = jbase + kt*32 + kg*8;
    float4 mk0 = *reinterpret_cast<const float4*>(mrow + jc);
    float4 mk1 = *reinterpret_cast<const float4*>(mrow + jc + 4);
    float4 a20 = *reinterpret_cast<const float4*>(a2f + jc);
    float4 a21 = *reinterpret_cast<const float4*>(a2f + jc + 4);
    float a2l[8] = {a20.x,a20.y,a20.z,a20.w,a21.x,a21.y,a21.z,a21.w};
    float mkl[8] = {mk0.x,mk0.y,mk0.z,mk0.w,mk1.x,mk1.y,mk1.z,mk1.w};
    float wv[8];
    #pragma unroll
    for (int e=0;e<8;++e){
      float p = __expf(leaky(a1v + a2l[e]) - mv) * mkl[e];
      wv[e] = p; dsum += p;
    }
    BU A;
    #pragma unroll
    for (int q=0;q<4;++q) A.u[q] = f2bf(wv[2*q]) | (f2bf(wv[2*q+1])<<16);
    #pragma unroll
    for (int ct=0; ct<8; ++ct){
      BU B; B.q = *reinterpret_cast<const uint4*>(ftfS + ((size_t)(g*16+kt)*8 + ct)*512 + lane*8);
      acc[ct] = __builtin_amdgcn_mfma_f32_16x16x32_bf16(A.v, B.v, acc[ct], 0, 0, 0);
    }
  }
  dsum += __shfl_xor(dsum, 16);
  dsum += __shfl_xor(dsum, 32);
  if (lane < 16) s_d[w][lane] = dsum;
  #pragma unroll
  for (int ct=0; ct<8; ++ct)
    *reinterpret_cast<float4*>(&s_acc[w][ct][lane][0]) = (float4){acc[ct][0],acc[ct][1],acc[ct][2],acc[ct][3]};
  __syncthreads();
  float dt = s_d[0][row] + s_d[1][row] + EPSV;
  #pragma unroll
  for (int ci=0; ci<4; ++ci){
    int ct = w*4 + ci;
    float4 A0 = *reinterpret_cast<float4*>(&s_acc[0][ct][lane][0]);
    float4 A1 = *reinterpret_cast<float4*>(&s_acc[1][ct][lane][0]);
    float tot[4] = {A0.x+A1.x, A0.y+A1.y, A0.z+A1.z, A0.w+A1.w};
    float psum = 0.f;
    #pragma unroll
    for (int reg=0; reg<4; ++reg){
      float drow = __shfl(dt, kg*4+reg);
      psum += eluf(tot[reg] / drow);
    }
    psum += __shfl_xor(psum, 16);
    psum += __shfl_xor(psum, 32);
    if (lane < 16) ppart[(size_t)b*DMID + ct*16 + lane] = psum;
  }
}

// ---------- K5: reduce ppart + MLP ----------
__global__ __launch_bounds__(128) void k_mlp(
    const float* __restrict__ ppart, const float* __restrict__ W1, const float* __restrict__ b1,
    const float* __restrict__ W2, const float* __restrict__ b2, float* __restrict__ out){
  int g = blockIdx.x;
  int t = threadIdx.x;
  __shared__ float ps[DMID], ts[DMID];
  float s = 0.f;
  #pragma unroll 8
  for (int it=0; it<32; ++it) s += ppart[(size_t)(g*32+it)*DMID + t];
  ps[t] = s;
  __syncthreads();
  float acc = b1[t];
  #pragma unroll 8
  for (int k=0;k<DMID;++k) acc += ps[k]*W1[k*DMID+t];
  ts[t] = fmaxf(acc, 0.f);
  __syncthreads();
  if (t < 16){
    float o = b2[t];
    #pragma unroll 8
    for (int k=0;k<DMID;++k) o += ts[k]*W2[k*16+t];
    out[g*16+t] = o;
  }
}

extern "C" void kernel_launch(void* const* d_in, const int* in_sizes, int n_in,
                              void* d_out, int out_size, void* d_ws, size_t ws_size,
                              hipStream_t stream) {
  const float* x    = (const float*)d_in[0];
  const float* mask = (const float*)d_in[1];
  const float* Wv   = (const float*)d_in[3];
  const float* bv   = (const float*)d_in[4];
  const float* W0   = (const float*)d_in[5];
  const float* al0  = (const float*)d_in[6];
  const float* ar0  = (const float*)d_in[7];
  const float* Wf   = (const float*)d_in[8];
  const float* alf  = (const float*)d_in[9];
  const float* arf  = (const float*)d_in[10];
  const float* W1   = (const float*)d_in[11];
  const float* b1   = (const float*)d_in[12];
  const float* W2   = (const float*)d_in[13];
  const float* b2   = (const float*)d_in[14];
  float* out = (float*)d_out;

  char* W = (char*)d_ws;
  ushort_t* WvS  = (ushort_t*)(W);              // 32768 B
  ushort_t* W0S  = (ushort_t*)(W + 32768);      // 65536 B
  ushort_t* WfS  = (ushort_t*)(W + 98304);      // 65536 B
  ushort_t* ftS  = (ushort_t*)(W + 163840);     // 3145728 B
  ushort_t* ftfS = (ushort_t*)(W + 3309568);    // 1572864 B
  ushort_t* h1b  = (ushort_t*)(W + 4882432);    // 3145728 B
  float* a1arr = (float*)(W + 8028160);         // 98304 B
  float* a2arr = (float*)(W + 8126464);         // 98304 B
  float* a1f   = (float*)(W + 8224768);         // 24576 B
  float* a2f   = (float*)(W + 8249344);         // 24576 B
  float* pmax0 = (float*)(W + 8273920);         // 6144 B
  float* pmaxf = (float*)(W + 8280064);         // 1536 B
  float* ppart = (float*)(W + 8281600);         // 196608 B

  hipLaunchKernelGGL(k_prep,  dim3(40),       dim3(256), 0, stream, Wv, W0, Wf, WvS, W0S, WfS);
  hipLaunchKernelGGL(k_f1,    dim3(Nn/16),    dim3(256), 0, stream,
                     x, bv, WvS, W0S, al0, ar0, ftS, a1arr, a2arr, pmax0);
  hipLaunchKernelGGL(k_attn0, dim3(NG*NH*32), dim3(64),  0, stream,
                     ftS, a1arr, a2arr, pmax0, mask, h1b);
  hipLaunchKernelGGL(k_fcf,   dim3(Nn/16),    dim3(256), 0, stream,
                     h1b, WfS, alf, arf, ftfS, a1f, a2f, pmaxf);
  hipLaunchKernelGGL(k_attnf, dim3(NG*32),    dim3(128), 0, stream,
                     ftfS, a1f, a2f, pmaxf, mask, ppart);
  hipLaunchKernelGGL(k_mlp,   dim3(NG),       dim3(128), 0, stream,
                     ppart, W1, b1, W2, b2, out);
}

// Round 5
// 57.496 us; speedup vs baseline: 4.9281x; 1.3097x over previous
//
#include <hip/hip_runtime.h>
#include <math.h>

#define Nn 6144
#define FIN 128
#define DMID 128
#define DHID 64
#define NH 4
#define NG 12
#define NB 512
#define ALPHA 0.2f
#define EPSV 1e-9f

typedef __bf16 bf16x8 __attribute__((ext_vector_type(8)));
typedef float f32x4 __attribute__((ext_vector_type(4)));
typedef unsigned short ushort_t;

union BU { bf16x8 v; uint u[4]; uint4 q; };

__device__ __forceinline__ float leaky(float x){ return x > 0.f ? x : ALPHA*x; }
__device__ __forceinline__ float eluf(float x){ return x > 0.f ? x : __expf(x)-1.f; }
__device__ __forceinline__ uint f2bf(float f){
  uint u = __float_as_uint(f);
  return (u + 0x7FFFu + ((u>>16)&1u)) >> 16;
}
__device__ __forceinline__ float wave_max(float v){
  #pragma unroll
  for (int off=32; off; off>>=1) v = fmaxf(v, __shfl_xor(v, off));
  return v;
}

// ---------- K0: swizzle weights into MFMA B-fragment order (bf16) ----------
__global__ __launch_bounds__(256) void k_prep(
    const float* __restrict__ Wv, const float* __restrict__ W0, const float* __restrict__ Wf,
    ushort_t* __restrict__ WvS, ushort_t* __restrict__ W0S, ushort_t* __restrict__ WfS){
  int tid = blockIdx.x*256 + threadIdx.x;
  int lane = tid & 63, blk = tid >> 6;
  if (blk >= 160) return;
  const float* src; ushort_t* dst; int N; size_t off;
  if (blk < 32){
    int nt = blk>>2, kt = blk&3;
    src = Wv; dst = WvS; N = 128;
    off = ((size_t)(nt*4+kt)*64 + lane)*8;
    int col = nt*16 + (lane&15); int k0 = kt*32 + (lane>>4)*8;
    uint4 pk;
    uint e0=f2bf(src[(k0+0)*N+col]), e1=f2bf(src[(k0+1)*N+col]);
    uint e2=f2bf(src[(k0+2)*N+col]), e3=f2bf(src[(k0+3)*N+col]);
    uint e4=f2bf(src[(k0+4)*N+col]), e5=f2bf(src[(k0+5)*N+col]);
    uint e6=f2bf(src[(k0+6)*N+col]), e7=f2bf(src[(k0+7)*N+col]);
    pk.x=e0|(e1<<16); pk.y=e2|(e3<<16); pk.z=e4|(e5<<16); pk.w=e6|(e7<<16);
    *reinterpret_cast<uint4*>(dst + off) = pk;
  } else if (blk < 96){
    int b2 = blk-32; int hd = b2>>4, r = b2&15; int nt = r>>2, kt = r&3;
    src = W0 + (size_t)hd*128*64; dst = W0S + (size_t)hd*8192; N = 64;
    off = ((size_t)(nt*4+kt)*64 + lane)*8;
    int col = nt*16 + (lane&15); int k0 = kt*32 + (lane>>4)*8;
    uint4 pk;
    uint e0=f2bf(src[(k0+0)*N+col]), e1=f2bf(src[(k0+1)*N+col]);
    uint e2=f2bf(src[(k0+2)*N+col]), e3=f2bf(src[(k0+3)*N+col]);
    uint e4=f2bf(src[(k0+4)*N+col]), e5=f2bf(src[(k0+5)*N+col]);
    uint e6=f2bf(src[(k0+6)*N+col]), e7=f2bf(src[(k0+7)*N+col]);
    pk.x=e0|(e1<<16); pk.y=e2|(e3<<16); pk.z=e4|(e5<<16); pk.w=e6|(e7<<16);
    *reinterpret_cast<uint4*>(dst + off) = pk;
  } else {
    int b2 = blk-96; int nt = b2>>3, kt = b2&7;
    src = Wf; dst = WfS; N = 128;
    off = ((size_t)(nt*8+kt)*64 + lane)*8;
    int col = nt*16 + (lane&15); int k0 = kt*32 + (lane>>4)*8;
    uint4 pk;
    uint e0=f2bf(src[(k0+0)*N+col]), e1=f2bf(src[(k0+1)*N+col]);
    uint e2=f2bf(src[(k0+2)*N+col]), e3=f2bf(src[(k0+3)*N+col]);
    uint e4=f2bf(src[(k0+4)*N+col]), e5=f2bf(src[(k0+5)*N+col]);
    uint e6=f2bf(src[(k0+6)*N+col]), e7=f2bf(src[(k0+7)*N+col]);
    pk.x=e0|(e1<<16); pk.y=e2|(e3<<16); pk.z=e4|(e5<<16); pk.w=e6|(e7<<16);
    *reinterpret_cast<uint4*>(dst + off) = pk;
  }
}

// ---------- K1: fc1 + ft0 (MFMA) + dots + swizzled ftS ----------
__global__ __launch_bounds__(256) void k_f1(
    const float* __restrict__ x, const float* __restrict__ bv,
    const ushort_t* __restrict__ WvS, const ushort_t* __restrict__ W0S,
    const float* __restrict__ al0, const float* __restrict__ ar0,
    ushort_t* __restrict__ ftS, float* __restrict__ a1arr, float* __restrict__ a2arr,
    float* __restrict__ pmax0){
  int b = blockIdx.x; int i0 = b*16;
  int t = threadIdx.x, lane = t&63, w = t>>6;
  int row = lane&15, kg = lane>>4;
  __shared__ ushort_t xs[16][136];
  __shared__ ushort_t hts[16][136];
  __shared__ ushort_t fts[16][264];
  {
    const float* xp = x + (size_t)i0*FIN + t*8;
    float4 f0 = *reinterpret_cast<const float4*>(xp);
    float4 f1 = *reinterpret_cast<const float4*>(xp+4);
    uint4 pk;
    pk.x = f2bf(f0.x)|(f2bf(f0.y)<<16); pk.y = f2bf(f0.z)|(f2bf(f0.w)<<16);
    pk.z = f2bf(f1.x)|(f2bf(f1.y)<<16); pk.w = f2bf(f1.z)|(f2bf(f1.w)<<16);
    *reinterpret_cast<uint4*>(&xs[t>>4][(t&15)*8]) = pk;
  }
  __syncthreads();
  {
    f32x4 acc2[2] = {{0,0,0,0},{0,0,0,0}};
    #pragma unroll
    for (int kt=0; kt<4; ++kt){
      bf16x8 aF = *reinterpret_cast<bf16x8*>(&xs[row][kt*32 + kg*8]);
      #pragma unroll
      for (int e2=0; e2<2; ++e2){
        int nt = w*2+e2;
        BU B; B.q = *reinterpret_cast<const uint4*>(WvS + ((size_t)(nt*4+kt)*64 + lane)*8);
        acc2[e2] = __builtin_amdgcn_mfma_f32_16x16x32_bf16(aF, B.v, acc2[e2], 0, 0, 0);
      }
    }
    #pragma unroll
    for (int e2=0; e2<2; ++e2){
      int nt = w*2+e2;
      float bvv = bv[nt*16+row];
      #pragma unroll
      for (int reg=0; reg<4; ++reg){
        float v = fmaxf(acc2[e2][reg]+bvv, 0.f);
        hts[kg*4+reg][nt*16+row] = (ushort_t)f2bf(v);
      }
    }
  }
  __syncthreads();
  f32x4 acc4[4] = {{0,0,0,0},{0,0,0,0},{0,0,0,0},{0,0,0,0}};
  #pragma unroll
  for (int kt=0; kt<4; ++kt){
    bf16x8 aF = *reinterpret_cast<bf16x8*>(&hts[row][kt*32 + kg*8]);
    #pragma unroll
    for (int nt=0; nt<4; ++nt){
      BU B; B.q = *reinterpret_cast<const uint4*>(W0S + ((size_t)((w*4+nt)*4+kt)*64 + lane)*8);
      acc4[nt] = __builtin_amdgcn_mfma_f32_16x16x32_bf16(aF, B.v, acc4[nt], 0, 0, 0);
    }
  }
  {
    float alv[4], arv[4];
    #pragma unroll
    for (int nt=0; nt<4; ++nt){ alv[nt] = al0[w*DHID+nt*16+row]; arv[nt] = ar0[w*DHID+nt*16+row]; }
    float s1[4]={0,0,0,0}, s2[4]={0,0,0,0};
    #pragma unroll
    for (int nt=0; nt<4; ++nt)
      #pragma unroll
      for (int reg=0; reg<4; ++reg){
        s1[reg] += acc4[nt][reg]*alv[nt];
        s2[reg] += acc4[nt][reg]*arv[nt];
      }
    #pragma unroll
    for (int off=1; off<16; off<<=1)
      #pragma unroll
      for (int reg=0; reg<4; ++reg){
        s1[reg] += __shfl_xor(s1[reg], off);
        s2[reg] += __shfl_xor(s2[reg], off);
      }
    if (row==0){
      #pragma unroll
      for (int reg=0; reg<4; ++reg){
        a1arr[w*Nn + i0 + kg*4+reg] = s1[reg];
        a2arr[w*Nn + i0 + kg*4+reg] = s2[reg];
      }
    }
    float mm = fmaxf(fmaxf(s2[0],s2[1]), fmaxf(s2[2],s2[3]));
    mm = fmaxf(mm, __shfl_xor(mm,16));
    mm = fmaxf(mm, __shfl_xor(mm,32));
    if (lane==0) pmax0[w*384 + b] = mm;
  }
  #pragma unroll
  for (int nt=0; nt<4; ++nt)
    #pragma unroll
    for (int reg=0; reg<4; ++reg)
      fts[kg*4+reg][w*DHID + nt*16+row] = (ushort_t)f2bf(acc4[nt][reg]);
  __syncthreads();
  {
    int ch = t, hd2 = ch>>6, ct = (ch>>4)&3, c = ch&15;
    int g = b>>5, ktj = (b&31)>>1, half = b&1;
    ushort_t v[16];
    #pragma unroll
    for (int i=0; i<16; ++i) v[i] = fts[i][ch];
    uint4 p0, p1;
    p0.x=(uint)v[0]|((uint)v[1]<<16);  p0.y=(uint)v[2]|((uint)v[3]<<16);
    p0.z=(uint)v[4]|((uint)v[5]<<16);  p0.w=(uint)v[6]|((uint)v[7]<<16);
    p1.x=(uint)v[8]|((uint)v[9]<<16);  p1.y=(uint)v[10]|((uint)v[11]<<16);
    p1.z=(uint)v[12]|((uint)v[13]<<16);p1.w=(uint)v[14]|((uint)v[15]<<16);
    size_t base = (((size_t)(g*4+hd2)*16 + ktj)*4 + ct)*512;
    *reinterpret_cast<uint4*>(ftS + base + ((half*2+0)*16+c)*8) = p0;
    *reinterpret_cast<uint4*>(ftS + base + ((half*2+1)*16+c)*8) = p1;
  }
}

// ---------- K2: fused attention-0 (4 heads x 2 j-halves) + fcf + dots + swizzled ftfS ----------
__global__ __launch_bounds__(512) void k_attn0fcf(
    const ushort_t* __restrict__ ftS, const float* __restrict__ a1arr,
    const float* __restrict__ a2arr, const float* __restrict__ pmax0,
    const float* __restrict__ mask, const ushort_t* __restrict__ WfS,
    const float* __restrict__ alf, const float* __restrict__ arf,
    ushort_t* __restrict__ ftfS, float* __restrict__ a1f, float* __restrict__ a2f,
    float* __restrict__ pmaxf){
  int b = blockIdx.x;            // 384 = g*32 + it
  int g = b>>5, it = b&31;
  int i0 = g*NB + it*16, jbase = g*NB;
  int t = threadIdx.x, lane = t&63, w = t>>6;
  int hd = w>>1, jh = w&1;
  int row = lane&15, kg = lane>>4;

  __shared__ float aacc[8][4][64][4];    // 32 KB
  __shared__ float ad[8][16];
  __shared__ ushort_t h1s[16][264];      // 8.4 KB
  __shared__ ushort_t fts[16][136];      // 4.3 KB
  __shared__ float dpA[8][16], dpB[8][16];

  // ---- phase A: scores + PV (head hd, j-half jh) ----
  {
    float mxv = -INFINITY;
    #pragma unroll
    for (int q=0; q<6; ++q) mxv = fmaxf(mxv, pmax0[hd*384 + q*64 + lane]);
    mxv = wave_max(mxv);
    float a1v = a1arr[hd*Nn + i0 + row];
    float mv = leaky(a1v + mxv);
    f32x4 acc[4] = {{0,0,0,0},{0,0,0,0},{0,0,0,0},{0,0,0,0}};
    float dsum = 0.f;
    const float* mrow = mask + (size_t)(i0+row)*Nn;
    size_t fbase = ((size_t)(g*4+hd)*16*4)*512;
    #pragma unroll 2
    for (int c8=0; c8<8; ++c8){
      int kt = jh*8 + c8;
      int jc = jbase + kt*32 + kg*8;
      float4 mk0 = *reinterpret_cast<const float4*>(mrow + jc);
      float4 mk1 = *reinterpret_cast<const float4*>(mrow + jc + 4);
      float4 a20 = *reinterpret_cast<const float4*>(a2arr + hd*Nn + jc);
      float4 a21 = *reinterpret_cast<const float4*>(a2arr + hd*Nn + jc + 4);
      float a2l[8] = {a20.x,a20.y,a20.z,a20.w,a21.x,a21.y,a21.z,a21.w};
      float mkl[8] = {mk0.x,mk0.y,mk0.z,mk0.w,mk1.x,mk1.y,mk1.z,mk1.w};
      float wv[8];
      #pragma unroll
      for (int e=0;e<8;++e){
        float p = __expf(leaky(a1v + a2l[e]) - mv) * mkl[e];
        wv[e] = p; dsum += p;
      }
      BU A;
      #pragma unroll
      for (int q=0;q<4;++q) A.u[q] = f2bf(wv[2*q]) | (f2bf(wv[2*q+1])<<16);
      #pragma unroll
      for (int ct=0; ct<4; ++ct){
        BU B; B.q = *reinterpret_cast<const uint4*>(ftS + fbase + (size_t)(kt*4+ct)*512 + lane*8);
        acc[ct] = __builtin_amdgcn_mfma_f32_16x16x32_bf16(A.v, B.v, acc[ct], 0, 0, 0);
      }
    }
    dsum += __shfl_xor(dsum, 16);
    dsum += __shfl_xor(dsum, 32);
    if (lane < 16) ad[w][lane] = dsum;
    #pragma unroll
    for (int ct=0; ct<4; ++ct)
      *reinterpret_cast<float4*>(&aacc[w][ct][lane][0]) = (float4){acc[ct][0],acc[ct][1],acc[ct][2],acc[ct][3]};
  }
  __syncthreads();
  // ---- phase B: combine j-halves, ELU, write h1 tile (bf16 LDS) ----
  {
    int w0 = hd*2, w1 = hd*2+1;
    float dr[4];
    #pragma unroll
    for (int reg=0; reg<4; ++reg) dr[reg] = ad[w0][kg*4+reg] + ad[w1][kg*4+reg] + EPSV;
    #pragma unroll
    for (int ci=0; ci<2; ++ci){
      int ct = jh*2+ci;
      float4 A0 = *reinterpret_cast<float4*>(&aacc[w0][ct][lane][0]);
      float4 A1 = *reinterpret_cast<float4*>(&aacc[w1][ct][lane][0]);
      float tot[4] = {A0.x+A1.x, A0.y+A1.y, A0.z+A1.z, A0.w+A1.w};
      #pragma unroll
      for (int reg=0; reg<4; ++reg){
        float o = eluf(tot[reg]/dr[reg]);
        h1s[kg*4+reg][hd*64 + ct*16 + row] = (ushort_t)f2bf(o);
      }
    }
  }
  __syncthreads();
  // ---- phase C: fcf (wave w -> n-tile w), dots ----
  {
    f32x4 acc2 = {0,0,0,0};
    #pragma unroll
    for (int kt=0; kt<8; ++kt){
      bf16x8 aF = *reinterpret_cast<bf16x8*>(&h1s[row][kt*32 + kg*8]);
      BU B; B.q = *reinterpret_cast<const uint4*>(WfS + ((size_t)(w*8+kt)*64 + lane)*8);
      acc2 = __builtin_amdgcn_mfma_f32_16x16x32_bf16(aF, B.v, acc2, 0, 0, 0);
    }
    float alv = alf[w*16+row], arv = arf[w*16+row];
    float s1[4], s2[4];
    #pragma unroll
    for (int reg=0; reg<4; ++reg){
      s1[reg] = acc2[reg]*alv;
      s2[reg] = acc2[reg]*arv;
      fts[kg*4+reg][w*16+row] = (ushort_t)f2bf(acc2[reg]);
    }
    #pragma unroll
    for (int off=1; off<16; off<<=1)
      #pragma unroll
      for (int reg=0; reg<4; ++reg){
        s1[reg] += __shfl_xor(s1[reg], off);
        s2[reg] += __shfl_xor(s2[reg], off);
      }
    if (row==0){
      #pragma unroll
      for (int reg=0; reg<4; ++reg){ dpA[w][kg*4+reg]=s1[reg]; dpB[w][kg*4+reg]=s2[reg]; }
    }
  }
  __syncthreads();
  if (t < 16){
    float v1=0.f, v2=0.f;
    #pragma unroll
    for (int q=0; q<8; ++q){ v1 += dpA[q][t]; v2 += dpB[q][t]; }
    a1f[i0+t] = v1; a2f[i0+t] = v2;
    float m = v2;
    #pragma unroll
    for (int off=1; off<16; off<<=1) m = fmaxf(m, __shfl_xor(m, off));
    if (t==0) pmaxf[b] = m;
  }
  // ---- swizzled ftfS write (first 256 threads) ----
  if (t < 256){
    int ch = t>>1, half8 = t&1;
    int ct = ch>>4, c = ch&15;
    int gg = b>>5, ktj = (b&31)>>1, half = b&1;
    ushort_t v[8];
    #pragma unroll
    for (int i=0; i<8; ++i) v[i] = fts[half8*8+i][ch];
    uint4 pk;
    pk.x=(uint)v[0]|((uint)v[1]<<16); pk.y=(uint)v[2]|((uint)v[3]<<16);
    pk.z=(uint)v[4]|((uint)v[5]<<16); pk.w=(uint)v[6]|((uint)v[7]<<16);
    int kslot = half*2 + half8;
    size_t base = ((size_t)(gg*16+ktj)*8 + ct)*512;
    *reinterpret_cast<uint4*>(ftfS + base + (kslot*16+c)*8) = pk;
  }
}

// ---------- K3: final attention (MFMA, 4-way j-split) + pool partials ----------
__global__ __launch_bounds__(256) void k_attnf(
    const ushort_t* __restrict__ ftfS, const float* __restrict__ a1f,
    const float* __restrict__ a2f, const float* __restrict__ pmaxf,
    const float* __restrict__ mask, float* __restrict__ ppart){
  int b = blockIdx.x;             // 384: g, it
  int g = b>>5, it = b&31;
  int i0 = g*NB + it*16, jbase = g*NB;
  int t = threadIdx.x, lane = t&63, w = t>>6;
  int row = lane&15, kg = lane>>4;
  __shared__ float s_acc[4][8][64][4];   // 32 KB
  __shared__ float s_d[4][16];
  float mxv = -INFINITY;
  #pragma unroll
  for (int q=0; q<6; ++q) mxv = fmaxf(mxv, pmaxf[q*64 + lane]);
  mxv = wave_max(mxv);
  float a1v = a1f[i0+row];
  float mv = leaky(a1v + mxv);
  f32x4 acc[8];
  #pragma unroll
  for (int ct=0; ct<8; ++ct) acc[ct] = (f32x4){0,0,0,0};
  float dsum = 0.f;
  const float* mrow = mask + (size_t)(i0+row)*Nn;
  #pragma unroll 2
  for (int c4=0; c4<4; ++c4){
    int kt = w*4 + c4;
    int jc = jbase + kt*32 + kg*8;
    float4 mk0 = *reinterpret_cast<const float4*>(mrow + jc);
    float4 mk1 = *reinterpret_cast<const float4*>(mrow + jc + 4);
    float4 a20 = *reinterpret_cast<const float4*>(a2f + jc);
    float4 a21 = *reinterpret_cast<const float4*>(a2f + jc + 4);
    float a2l[8] = {a20.x,a20.y,a20.z,a20.w,a21.x,a21.y,a21.z,a21.w};
    float mkl[8] = {mk0.x,mk0.y,mk0.z,mk0.w,mk1.x,mk1.y,mk1.z,mk1.w};
    float wv[8];
    #pragma unroll
    for (int e=0;e<8;++e){
      float p = __expf(leaky(a1v + a2l[e]) - mv) * mkl[e];
      wv[e] = p; dsum += p;
    }
    BU A;
    #pragma unroll
    for (int q=0;q<4;++q) A.u[q] = f2bf(wv[2*q]) | (f2bf(wv[2*q+1])<<16);
    #pragma unroll
    for (int ct=0; ct<8; ++ct){
      BU B; B.q = *reinterpret_cast<const uint4*>(ftfS + ((size_t)(g*16+kt)*8 + ct)*512 + lane*8);
      acc[ct] = __builtin_amdgcn_mfma_f32_16x16x32_bf16(A.v, B.v, acc[ct], 0, 0, 0);
    }
  }
  dsum += __shfl_xor(dsum, 16);
  dsum += __shfl_xor(dsum, 32);
  if (lane < 16) s_d[w][lane] = dsum;
  #pragma unroll
  for (int ct=0; ct<8; ++ct)
    *reinterpret_cast<float4*>(&s_acc[w][ct][lane][0]) = (float4){acc[ct][0],acc[ct][1],acc[ct][2],acc[ct][3]};
  __syncthreads();
  float dr[4];
  #pragma unroll
  for (int reg=0; reg<4; ++reg)
    dr[reg] = s_d[0][kg*4+reg] + s_d[1][kg*4+reg] + s_d[2][kg*4+reg] + s_d[3][kg*4+reg] + EPSV;
  #pragma unroll
  for (int ci=0; ci<2; ++ci){
    int ct = w*2 + ci;
    float4 A0 = *reinterpret_cast<float4*>(&s_acc[0][ct][lane][0]);
    float4 A1 = *reinterpret_cast<float4*>(&s_acc[1][ct][lane][0]);
    float4 A2 = *reinterpret_cast<float4*>(&s_acc[2][ct][lane][0]);
    float4 A3 = *reinterpret_cast<float4*>(&s_acc[3][ct][lane][0]);
    float tot[4] = {A0.x+A1.x+A2.x+A3.x, A0.y+A1.y+A2.y+A3.y,
                    A0.z+A1.z+A2.z+A3.z, A0.w+A1.w+A2.w+A3.w};
    float psum = 0.f;
    #pragma unroll
    for (int reg=0; reg<4; ++reg) psum += eluf(tot[reg]/dr[reg]);
    psum += __shfl_xor(psum, 16);
    psum += __shfl_xor(psum, 32);
    if (lane < 16) ppart[(size_t)b*DMID + ct*16 + lane] = psum;
  }
}

// ---------- K4: reduce ppart + MLP ----------
__global__ __launch_bounds__(256) void k_mlp(
    const float* __restrict__ ppart, const float* __restrict__ W1, const float* __restrict__ b1,
    const float* __restrict__ W2, const float* __restrict__ b2, float* __restrict__ out){
  int g = blockIdx.x;
  int t = threadIdx.x;
  __shared__ float red[8][DMID];
  __shared__ float ps[DMID], ts[DMID];
  __shared__ float p2[2][DMID];
  __shared__ float p4[2][16];
  {
    float4 s4 = {0,0,0,0};
    #pragma unroll
    for (int gi=0; gi<4; ++gi){
      int itx = (t>>5) + gi*8;
      float4 v = *reinterpret_cast<const float4*>(ppart + (size_t)(g*32+itx)*DMID + (t&31)*4);
      s4.x += v.x; s4.y += v.y; s4.z += v.z; s4.w += v.w;
    }
    *reinterpret_cast<float4*>(&red[t>>5][(t&31)*4]) = s4;
  }
  __syncthreads();
  if (t < DMID){
    float s = 0.f;
    #pragma unroll
    for (int q=0; q<8; ++q) s += red[q][t];
    ps[t] = s;
  }
  __syncthreads();
  {
    int col = t & 127, half = t>>7;
    float acc = 0.f;
    #pragma unroll 8
    for (int k=half*64; k<half*64+64; ++k) acc += ps[k]*W1[k*DMID+col];
    p2[half][col] = acc;
  }
  __syncthreads();
  if (t < DMID) ts[t] = fmaxf(p2[0][t]+p2[1][t]+b1[t], 0.f);
  __syncthreads();
  if (t < 32){
    int col = t & 15, half = t>>4;
    float acc = 0.f;
    #pragma unroll 8
    for (int k=half*64; k<half*64+64; ++k) acc += ts[k]*W2[k*16+col];
    p4[half][col] = acc;
  }
  __syncthreads();
  if (t < 16) out[g*16+t] = p4[0][t]+p4[1][t]+b2[t];
}

extern "C" void kernel_launch(void* const* d_in, const int* in_sizes, int n_in,
                              void* d_out, int out_size, void* d_ws, size_t ws_size,
                              hipStream_t stream) {
  const float* x    = (const float*)d_in[0];
  const float* mask = (const float*)d_in[1];
  const float* Wv   = (const float*)d_in[3];
  const float* bv   = (const float*)d_in[4];
  const float* W0   = (const float*)d_in[5];
  const float* al0  = (const float*)d_in[6];
  const float* ar0  = (const float*)d_in[7];
  const float* Wf   = (const float*)d_in[8];
  const float* alf  = (const float*)d_in[9];
  const float* arf  = (const float*)d_in[10];
  const float* W1   = (const float*)d_in[11];
  const float* b1   = (const float*)d_in[12];
  const float* W2   = (const float*)d_in[13];
  const float* b2   = (const float*)d_in[14];
  float* out = (float*)d_out;

  char* W = (char*)d_ws;
  ushort_t* WvS  = (ushort_t*)(W);              // 32768 B
  ushort_t* W0S  = (ushort_t*)(W + 32768);      // 65536 B
  ushort_t* WfS  = (ushort_t*)(W + 98304);      // 65536 B
  ushort_t* ftS  = (ushort_t*)(W + 163840);     // 3145728 B
  ushort_t* ftfS = (ushort_t*)(W + 3309568);    // 1572864 B
  float* a1arr = (float*)(W + 4882432);         // 98304 B
  float* a2arr = (float*)(W + 4980736);         // 98304 B
  float* a1f   = (float*)(W + 5079040);         // 24576 B
  float* a2f   = (float*)(W + 5103616);         // 24576 B
  float* pmax0 = (float*)(W + 5128192);         // 6144 B
  float* pmaxf = (float*)(W + 5134336);         // 1536 B
  float* ppart = (float*)(W + 5135872);         // 196608 B

  hipLaunchKernelGGL(k_prep,     dim3(40),    dim3(256), 0, stream, Wv, W0, Wf, WvS, W0S, WfS);
  hipLaunchKernelGGL(k_f1,       dim3(Nn/16), dim3(256), 0, stream,
                     x, bv, WvS, W0S, al0, ar0, ftS, a1arr, a2arr, pmax0);
  hipLaunchKernelGGL(k_attn0fcf, dim3(NG*32), dim3(512), 0, stream,
                     ftS, a1arr, a2arr, pmax0, mask, WfS, alf, arf, ftfS, a1f, a2f, pmaxf);
  hipLaunchKernelGGL(k_attnf,    dim3(NG*32), dim3(256), 0, stream,
                     ftfS, a1f, a2f, pmaxf, mask, ppart);
  hipLaunchKernelGGL(k_mlp,      dim3(NG),    dim3(256), 0, stream,
                     ppart, W1, b1, W2, b2, out);
}